// Round 1
// baseline (2352.925 us; speedup 1.0000x reference)
//
#include <hip/hip_runtime.h>
#include <hip/hip_bf16.h>
#include <math.h>

typedef float f4 __attribute__((ext_vector_type(4)));

#define BATCH 64
#define PP 500
#define NN 501

// ---------------- q projection: rows=B*P=32000, K=129, out 128 ----------------
__global__ __launch_bounds__(256) void k_proj_q(
    const float* __restrict__ Xn,   // [32000,128] encoded_last_node flat
    const float* __restrict__ Ld,   // [32000] load flat
    const float* __restrict__ Wq,   // [129,128]
    float* __restrict__ Q)          // [32000,128]
{
  __shared__ float xs[64*132];
  const int t = threadIdx.x;
  const int r0 = blockIdx.x * 64;
  for (int i = t; i < 64*32; i += 256) {
    int r = i >> 5, k4 = (i & 31) << 2;
    *(f4*)(xs + r*132 + k4) = *(const f4*)(Xn + (size_t)(r0+r)*128 + k4);
  }
  if (t < 64) xs[t*132 + 128] = Ld[r0 + t];
  __syncthreads();
  const int tr = t >> 5, tc = t & 31;
  float acc[8][4];
  #pragma unroll
  for (int i = 0; i < 8; i++)
    #pragma unroll
    for (int c = 0; c < 4; c++) acc[i][c] = 0.f;
  for (int k4 = 0; k4 < 128; k4 += 4) {
    f4 x[8], w[4];
    #pragma unroll
    for (int j = 0; j < 4; j++) w[j] = *(const f4*)(Wq + (size_t)(k4+j)*128 + tc*4);
    #pragma unroll
    for (int i = 0; i < 8; i++) x[i] = *(const f4*)(xs + (tr*8+i)*132 + k4);
    #pragma unroll
    for (int i = 0; i < 8; i++)
      #pragma unroll
      for (int j = 0; j < 4; j++)
        #pragma unroll
        for (int c = 0; c < 4; c++)
          acc[i][c] += x[i][j] * w[j][c];
  }
  { // tail k = 128 (the 'load' column)
    f4 w = *(const f4*)(Wq + (size_t)128*128 + tc*4);
    #pragma unroll
    for (int i = 0; i < 8; i++) {
      float xv = xs[(tr*8+i)*132 + 128];
      #pragma unroll
      for (int c = 0; c < 4; c++) acc[i][c] += xv * w[c];
    }
  }
  #pragma unroll
  for (int i = 0; i < 8; i++) {
    f4 o;
    #pragma unroll
    for (int c = 0; c < 4; c++) o[c] = acc[i][c];
    *(f4*)(Q + (size_t)(r0 + tr*8 + i)*128 + tc*4) = o;
  }
}

// ---------------- k & v projection: rows=B*N=32064, K=128 ----------------
__global__ __launch_bounds__(256) void k_proj_kv(
    const float* __restrict__ Xn,   // [32064,128] encoded_nodes flat
    const float* __restrict__ Wk, const float* __restrict__ Wv,
    float* __restrict__ K_, float* __restrict__ V_)
{
  __shared__ float xs[64*132];
  const int t = threadIdx.x;
  const int r0 = blockIdx.x * 64;
  for (int i = t; i < 64*32; i += 256) {
    int r = i >> 5, k4 = (i & 31) << 2;
    *(f4*)(xs + r*132 + k4) = *(const f4*)(Xn + (size_t)(r0+r)*128 + k4);
  }
  __syncthreads();
  const int tr = t >> 5, tc = t & 31;
  float accK[8][4], accV[8][4];
  #pragma unroll
  for (int i = 0; i < 8; i++)
    #pragma unroll
    for (int c = 0; c < 4; c++) { accK[i][c] = 0.f; accV[i][c] = 0.f; }
  for (int k4 = 0; k4 < 128; k4 += 4) {
    f4 x[8], wk[4], wv[4];
    #pragma unroll
    for (int j = 0; j < 4; j++) {
      wk[j] = *(const f4*)(Wk + (size_t)(k4+j)*128 + tc*4);
      wv[j] = *(const f4*)(Wv + (size_t)(k4+j)*128 + tc*4);
    }
    #pragma unroll
    for (int i = 0; i < 8; i++) x[i] = *(const f4*)(xs + (tr*8+i)*132 + k4);
    #pragma unroll
    for (int i = 0; i < 8; i++)
      #pragma unroll
      for (int j = 0; j < 4; j++)
        #pragma unroll
        for (int c = 0; c < 4; c++) {
          accK[i][c] += x[i][j] * wk[j][c];
          accV[i][c] += x[i][j] * wv[j][c];
        }
  }
  #pragma unroll
  for (int i = 0; i < 8; i++) {
    f4 ok, ov;
    #pragma unroll
    for (int c = 0; c < 4; c++) { ok[c] = accK[i][c]; ov[c] = accV[i][c]; }
    *(f4*)(K_ + (size_t)(r0 + tr*8 + i)*128 + tc*4) = ok;
    *(f4*)(V_ + (size_t)(r0 + tr*8 + i)*128 + tc*4) = ov;
  }
}

// ---------------- attention: per (b,h,quarter); wave-per-row online softmax ----------------
__global__ __launch_bounds__(256) void k_attn(
    const float* __restrict__ Q, const float* __restrict__ K_, const float* __restrict__ V_,
    const float* __restrict__ Msk, float* __restrict__ OC)
{
  __shared__ float ks[NN*17];
  __shared__ float vs[NN*17];
  const int blk = blockIdx.x;
  const int qtr = blk & 3, h = (blk >> 2) & 7, b = blk >> 5;
  const int t = threadIdx.x;
  const float* kb = K_ + ((size_t)b*NN)*128 + h*16;
  const float* vb = V_ + ((size_t)b*NN)*128 + h*16;
  for (int i = t; i < NN*4; i += 256) {
    int n = i >> 2, d4 = (i & 3) << 2;
    f4 kv = *(const f4*)(kb + (size_t)n*128 + d4);
    f4 vv = *(const f4*)(vb + (size_t)n*128 + d4);
    #pragma unroll
    for (int j = 0; j < 4; j++) { ks[n*17 + d4 + j] = kv[j]; vs[n*17 + d4 + j] = vv[j]; }
  }
  __syncthreads();
  const int wv = t >> 6, ln = t & 63;
  const int p0 = qtr * 125;
  for (int p = p0 + wv; p < p0 + 125; p += 4) {
    const float* qr = Q + ((size_t)(b*PP + p))*128 + h*16;
    f4 q[4];
    #pragma unroll
    for (int j = 0; j < 4; j++) q[j] = *(const f4*)(qr + j*4);
    const float* mr = Msk + ((size_t)(b*PP + p))*NN;
    float s[8];
    #pragma unroll
    for (int j = 0; j < 8; j++) {
      int n = j*64 + ln;
      float a = -INFINITY;
      if (n < NN) {
        const float* kr = ks + n*17;
        float acc = 0.f;
        #pragma unroll
        for (int jj = 0; jj < 4; jj++)
          #pragma unroll
          for (int d = 0; d < 4; d++)
            acc += q[jj][d] * kr[jj*4 + d];
        a = acc*0.25f + mr[n];
      }
      s[j] = a;
    }
    float m = s[0];
    #pragma unroll
    for (int j = 1; j < 8; j++) m = fmaxf(m, s[j]);
    #pragma unroll
    for (int o = 32; o > 0; o >>= 1) m = fmaxf(m, __shfl_xor(m, o));
    float e[8]; float l = 0.f;
    #pragma unroll
    for (int j = 0; j < 8; j++) { e[j] = __expf(s[j] - m); l += e[j]; }
    #pragma unroll
    for (int o = 32; o > 0; o >>= 1) l += __shfl_xor(l, o);
    float out[16];
    #pragma unroll
    for (int d = 0; d < 16; d++) out[d] = 0.f;
    #pragma unroll
    for (int j = 0; j < 8; j++) {
      int n = j*64 + ln;
      if (n < NN) {
        const float* vr = vs + n*17;
        #pragma unroll
        for (int d = 0; d < 16; d++) out[d] += e[j] * vr[d];
      }
    }
    #pragma unroll
    for (int d = 0; d < 16; d++)
      #pragma unroll
      for (int o = 32; o > 0; o >>= 1) out[d] += __shfl_xor(out[d], o);
    if (ln == 0) {
      float inv = 1.f / l;
      float* orow = OC + ((size_t)(b*PP + p))*128 + h*16;
      #pragma unroll
      for (int d4 = 0; d4 < 16; d4 += 4) {
        f4 o;
        #pragma unroll
        for (int c = 0; c < 4; c++) o[c] = out[d4+c]*inv;
        *(f4*)(orow + d4) = o;
      }
    }
  }
}

// ---------------- fused per-batch FFN chain ----------------
__global__ __launch_bounds__(256) void k_ffn(
    const float* __restrict__ OC, const float* __restrict__ Wn, const float* __restrict__ Bn,
    const float* __restrict__ Wn2, const float* __restrict__ Bn2,
    const float* __restrict__ Wm, const float* __restrict__ Bm,
    float* __restrict__ MH)
{
  __shared__ float xs[64*132];
  __shared__ float hs[64*132];
  const int blk = blockIdx.x; const int b = blk >> 3, rb = blk & 7;
  const int r0 = rb*64;
  const int nv = min(64, PP - r0);
  const int t = threadIdx.x;
  const int tr = t >> 5, tc = t & 31;
  const float* ocb = OC + (size_t)b*PP*128;
  for (int i = t; i < 64*32; i += 256) {
    int r = i >> 5, k4 = (i & 31) << 2;
    f4 v = {0.f,0.f,0.f,0.f};
    if (r < nv) v = *(const f4*)(ocb + (size_t)(r0+r)*128 + k4);
    *(f4*)(xs + r*132 + k4) = v;
  }
  __syncthreads();
  // GEMM1: relu(xs @ new[b] + bias)
  {
    const float* W1 = Wn + (size_t)b*16384;
    float acc[8][4];
    #pragma unroll
    for (int i = 0; i < 8; i++)
      #pragma unroll
      for (int c = 0; c < 4; c++) acc[i][c] = 0.f;
    for (int k4 = 0; k4 < 128; k4 += 4) {
      f4 x[8], w[4];
      #pragma unroll
      for (int j = 0; j < 4; j++) w[j] = *(const f4*)(W1 + (size_t)(k4+j)*128 + tc*4);
      #pragma unroll
      for (int i = 0; i < 8; i++) x[i] = *(const f4*)(xs + (tr*8+i)*132 + k4);
      #pragma unroll
      for (int i = 0; i < 8; i++)
        #pragma unroll
        for (int j = 0; j < 4; j++)
          #pragma unroll
          for (int c = 0; c < 4; c++)
            acc[i][c] += x[i][j] * w[j][c];
    }
    f4 b1 = *(const f4*)(Bn + b*128 + tc*4);
    #pragma unroll
    for (int i = 0; i < 8; i++) {
      f4 o;
      #pragma unroll
      for (int c = 0; c < 4; c++) o[c] = fmaxf(acc[i][c] + b1[c], 0.f);
      *(f4*)(hs + (tr*8+i)*132 + tc*4) = o;
    }
  }
  __syncthreads();
  // GEMM2: hs @ new_2[b] + bias2 + residual(xs)
  float h2[8][4];
  {
    const float* W2 = Wn2 + (size_t)b*16384;
    float acc[8][4];
    #pragma unroll
    for (int i = 0; i < 8; i++)
      #pragma unroll
      for (int c = 0; c < 4; c++) acc[i][c] = 0.f;
    for (int k4 = 0; k4 < 128; k4 += 4) {
      f4 x[8], w[4];
      #pragma unroll
      for (int j = 0; j < 4; j++) w[j] = *(const f4*)(W2 + (size_t)(k4+j)*128 + tc*4);
      #pragma unroll
      for (int i = 0; i < 8; i++) x[i] = *(const f4*)(hs + (tr*8+i)*132 + k4);
      #pragma unroll
      for (int i = 0; i < 8; i++)
        #pragma unroll
        for (int j = 0; j < 4; j++)
          #pragma unroll
          for (int c = 0; c < 4; c++)
            acc[i][c] += x[i][j] * w[j][c];
    }
    f4 b2 = *(const f4*)(Bn2 + b*128 + tc*4);
    #pragma unroll
    for (int i = 0; i < 8; i++)
      #pragma unroll
      for (int c = 0; c < 4; c++)
        h2[i][c] = acc[i][c] + b2[c] + xs[(tr*8+i)*132 + tc*4 + c];
  }
  __syncthreads();
  #pragma unroll
  for (int i = 0; i < 8; i++) {
    f4 o;
    #pragma unroll
    for (int c = 0; c < 4; c++) o[c] = h2[i][c];
    *(f4*)(hs + (tr*8+i)*132 + tc*4) = o;
  }
  __syncthreads();
  // GEMM3: hs @ mhc_W + mhc_b -> MH
  {
    float acc[8][4];
    #pragma unroll
    for (int i = 0; i < 8; i++)
      #pragma unroll
      for (int c = 0; c < 4; c++) acc[i][c] = 0.f;
    for (int k4 = 0; k4 < 128; k4 += 4) {
      f4 x[8], w[4];
      #pragma unroll
      for (int j = 0; j < 4; j++) w[j] = *(const f4*)(Wm + (size_t)(k4+j)*128 + tc*4);
      #pragma unroll
      for (int i = 0; i < 8; i++) x[i] = *(const f4*)(hs + (tr*8+i)*132 + k4);
      #pragma unroll
      for (int i = 0; i < 8; i++)
        #pragma unroll
        for (int j = 0; j < 4; j++)
          #pragma unroll
          for (int c = 0; c < 4; c++)
            acc[i][c] += x[i][j] * w[j][c];
    }
    f4 b3 = *(const f4*)(Bm + tc*4);
    #pragma unroll
    for (int i = 0; i < 8; i++) {
      if (tr*8 + i < nv) {
        f4 o;
        #pragma unroll
        for (int c = 0; c < 4; c++) o[c] = acc[i][c] + b3[c];
        *(f4*)(MH + ((size_t)b*PP + r0 + tr*8 + i)*128 + tc*4) = o;
      }
    }
  }
}

// ---------------- final: score2 GEMM + tanh clip + mask + softmax ----------------
__global__ __launch_bounds__(256) void k_final(
    const float* __restrict__ MH, const float* __restrict__ EN,
    const float* __restrict__ Msk, float* __restrict__ OUT)
{
  __shared__ float ms[32*132];
  __shared__ float es[64*132];
  __shared__ float sc[32*512];
  __shared__ float mrow[32], lrow[32];
  const int blk = blockIdx.x; const int b = blk >> 4, rb = blk & 15;
  const int r0 = rb*32; const int nv = min(32, PP - r0);
  const int t = threadIdx.x;
  const int tr = t >> 5, tc = t & 31;
  const float* mhb = MH + (size_t)(b*PP + r0)*128;
  for (int i = t; i < 32*32; i += 256) {
    int r = i >> 5, k4 = (i & 31) << 2;
    f4 v = {0.f,0.f,0.f,0.f};
    if (r < nv) v = *(const f4*)(mhb + (size_t)r*128 + k4);
    *(f4*)(ms + r*132 + k4) = v;
  }
  const float* enb = EN + (size_t)b*NN*128;
  const float* mkb = Msk + (size_t)(b*PP + r0)*NN;
  for (int nt = 0; nt < 8; nt++) {
    const int n0 = nt*64;
    __syncthreads();
    for (int i = t; i < 64*32; i += 256) {
      int n = i >> 5, k4 = (i & 31) << 2;
      f4 v = {0.f,0.f,0.f,0.f};
      if (n0 + n < NN) v = *(const f4*)(enb + (size_t)(n0+n)*128 + k4);
      *(f4*)(es + n*132 + k4) = v;
    }
    __syncthreads();
    float acc[4][2];
    #pragma unroll
    for (int i = 0; i < 4; i++) { acc[i][0] = 0.f; acc[i][1] = 0.f; }
    for (int k4 = 0; k4 < 128; k4 += 4) {
      f4 x[4];
      #pragma unroll
      for (int i = 0; i < 4; i++) x[i] = *(const f4*)(ms + (tr*4+i)*132 + k4);
      f4 e0 = *(const f4*)(es + tc*132 + k4);
      f4 e1 = *(const f4*)(es + (tc+32)*132 + k4);
      #pragma unroll
      for (int i = 0; i < 4; i++)
        #pragma unroll
        for (int j = 0; j < 4; j++) {
          acc[i][0] += x[i][j]*e0[j];
          acc[i][1] += x[i][j]*e1[j];
        }
    }
    #pragma unroll
    for (int i = 0; i < 4; i++) {
      int r = tr*4 + i;
      #pragma unroll
      for (int c = 0; c < 2; c++) {
        int n = n0 + tc + c*32;
        float val = 0.f;
        if (r < nv && n < NN) {
          // 10*tanh(s/sqrt(128)) = 10 - 20/(exp(s*2/sqrt(128)) + 1)  (NaN-free)
          float E = __expf(acc[i][c] * 0.17677669529663687f);
          val = 10.f - 20.f/(E + 1.f) + mkb[(size_t)r*NN + n];
        }
        sc[r*512 + n] = val;
      }
    }
  }
  __syncthreads();
  {
    const int r = t >> 3, sub = t & 7;
    float m = -INFINITY;
    for (int n = sub; n < NN; n += 8) m = fmaxf(m, sc[r*512 + n]);
    #pragma unroll
    for (int o = 1; o < 8; o <<= 1) m = fmaxf(m, __shfl_xor(m, o));
    float l = 0.f;
    for (int n = sub; n < NN; n += 8) l += __expf(sc[r*512 + n] - m);
    #pragma unroll
    for (int o = 1; o < 8; o <<= 1) l += __shfl_xor(l, o);
    if (sub == 0) { mrow[r] = m; lrow[r] = 1.f / l; }
  }
  __syncthreads();
  float* ob = OUT + (size_t)(b*PP + r0)*NN;
  for (int i = 0; i < 64; i++) {
    int idx = t + 256*i;
    int r = idx >> 9, n = idx & 511;
    if (r < nv && n < NN)
      ob[(size_t)r*NN + n] = __expf(sc[idx] - mrow[r]) * lrow[r];
  }
}

extern "C" void kernel_launch(void* const* d_in, const int* in_sizes, int n_in,
                              void* d_out, int out_size, void* d_ws, size_t ws_size,
                              hipStream_t stream) {
  const float* eln  = (const float*)d_in[0];
  const float* load = (const float*)d_in[1];
  const float* mask = (const float*)d_in[2];
  const float* en   = (const float*)d_in[3];
  const float* Wq   = (const float*)d_in[4];
  const float* Wk   = (const float*)d_in[5];
  const float* Wv   = (const float*)d_in[6];
  const float* Wm   = (const float*)d_in[7];
  const float* Bm   = (const float*)d_in[8];
  const float* Wn   = (const float*)d_in[9];
  const float* Bn   = (const float*)d_in[10];
  const float* Wn2  = (const float*)d_in[11];
  const float* Bn2  = (const float*)d_in[12];
  float* out = (float*)d_out;
  float* ws  = (float*)d_ws;
  float* Q   = ws;
  float* K_  = ws + 4096000;     // 64*500*128
  float* V_  = ws + 8200192;     // + 64*501*128
  float* OC  = ws + 12304384;    // + 64*501*128
  float* MH  = ws + 16400384;    // + 64*500*128
  hipLaunchKernelGGL(k_proj_q,  dim3(500),  dim3(256), 0, stream, eln, load, Wq, Q);
  hipLaunchKernelGGL(k_proj_kv, dim3(501),  dim3(256), 0, stream, en, Wk, Wv, K_, V_);
  hipLaunchKernelGGL(k_attn,    dim3(2048), dim3(256), 0, stream, Q, K_, V_, mask, OC);
  hipLaunchKernelGGL(k_ffn,     dim3(512),  dim3(256), 0, stream, OC, Wn, Bn, Wn2, Bn2, Wm, Bm, MH);
  hipLaunchKernelGGL(k_final,   dim3(1024), dim3(256), 0, stream, MH, en, mask, out);
}

// Round 2
// 942.901 us; speedup vs baseline: 2.4954x; 2.4954x over previous
//
#include <hip/hip_runtime.h>
#include <hip/hip_bf16.h>
#include <math.h>

typedef float f4 __attribute__((ext_vector_type(4)));

#define BATCH 64
#define PP 500
#define NN 501

// ---------------- q projection: rows=B*P=32000, K=129, out 128 ----------------
__global__ __launch_bounds__(256) void k_proj_q(
    const float* __restrict__ Xn,   // [32000,128] encoded_last_node flat
    const float* __restrict__ Ld,   // [32000] load flat
    const float* __restrict__ Wq,   // [129,128]
    float* __restrict__ Q)          // [32000,128]
{
  __shared__ float xs[64*132];
  const int t = threadIdx.x;
  const int r0 = blockIdx.x * 64;
  for (int i = t; i < 64*32; i += 256) {
    int r = i >> 5, k4 = (i & 31) << 2;
    *(f4*)(xs + r*132 + k4) = *(const f4*)(Xn + (size_t)(r0+r)*128 + k4);
  }
  if (t < 64) xs[t*132 + 128] = Ld[r0 + t];
  __syncthreads();
  const int tr = t >> 5, tc = t & 31;
  float acc[8][4];
  #pragma unroll
  for (int i = 0; i < 8; i++)
    #pragma unroll
    for (int c = 0; c < 4; c++) acc[i][c] = 0.f;
  for (int k4 = 0; k4 < 128; k4 += 4) {
    f4 x[8], w[4];
    #pragma unroll
    for (int j = 0; j < 4; j++) w[j] = *(const f4*)(Wq + (size_t)(k4+j)*128 + tc*4);
    #pragma unroll
    for (int i = 0; i < 8; i++) x[i] = *(const f4*)(xs + (tr*8+i)*132 + k4);
    #pragma unroll
    for (int i = 0; i < 8; i++)
      #pragma unroll
      for (int j = 0; j < 4; j++)
        #pragma unroll
        for (int c = 0; c < 4; c++)
          acc[i][c] += x[i][j] * w[j][c];
  }
  { // tail k = 128 (the 'load' column)
    f4 w = *(const f4*)(Wq + (size_t)128*128 + tc*4);
    #pragma unroll
    for (int i = 0; i < 8; i++) {
      float xv = xs[(tr*8+i)*132 + 128];
      #pragma unroll
      for (int c = 0; c < 4; c++) acc[i][c] += xv * w[c];
    }
  }
  #pragma unroll
  for (int i = 0; i < 8; i++) {
    f4 o;
    #pragma unroll
    for (int c = 0; c < 4; c++) o[c] = acc[i][c];
    *(f4*)(Q + (size_t)(r0 + tr*8 + i)*128 + tc*4) = o;
  }
}

// ---------------- k & v projection: rows=B*N=32064, K=128 ----------------
__global__ __launch_bounds__(256) void k_proj_kv(
    const float* __restrict__ Xn,   // [32064,128] encoded_nodes flat
    const float* __restrict__ Wk, const float* __restrict__ Wv,
    float* __restrict__ K_, float* __restrict__ V_)
{
  __shared__ float xs[64*132];
  const int t = threadIdx.x;
  const int r0 = blockIdx.x * 64;
  for (int i = t; i < 64*32; i += 256) {
    int r = i >> 5, k4 = (i & 31) << 2;
    *(f4*)(xs + r*132 + k4) = *(const f4*)(Xn + (size_t)(r0+r)*128 + k4);
  }
  __syncthreads();
  const int tr = t >> 5, tc = t & 31;
  float accK[8][4], accV[8][4];
  #pragma unroll
  for (int i = 0; i < 8; i++)
    #pragma unroll
    for (int c = 0; c < 4; c++) { accK[i][c] = 0.f; accV[i][c] = 0.f; }
  for (int k4 = 0; k4 < 128; k4 += 4) {
    f4 x[8], wk[4], wv[4];
    #pragma unroll
    for (int j = 0; j < 4; j++) {
      wk[j] = *(const f4*)(Wk + (size_t)(k4+j)*128 + tc*4);
      wv[j] = *(const f4*)(Wv + (size_t)(k4+j)*128 + tc*4);
    }
    #pragma unroll
    for (int i = 0; i < 8; i++) x[i] = *(const f4*)(xs + (tr*8+i)*132 + k4);
    #pragma unroll
    for (int i = 0; i < 8; i++)
      #pragma unroll
      for (int j = 0; j < 4; j++)
        #pragma unroll
        for (int c = 0; c < 4; c++) {
          accK[i][c] += x[i][j] * wk[j][c];
          accV[i][c] += x[i][j] * wv[j][c];
        }
  }
  #pragma unroll
  for (int i = 0; i < 8; i++) {
    f4 ok, ov;
    #pragma unroll
    for (int c = 0; c < 4; c++) { ok[c] = accK[i][c]; ov[c] = accV[i][c]; }
    *(f4*)(K_ + (size_t)(r0 + tr*8 + i)*128 + tc*4) = ok;
    *(f4*)(V_ + (size_t)(r0 + tr*8 + i)*128 + tc*4) = ov;
  }
}

// ---------------- attention: per (b,h,quarter); wave-per-row online softmax ----------------
__global__ __launch_bounds__(256) void k_attn(
    const float* __restrict__ Q, const float* __restrict__ K_, const float* __restrict__ V_,
    const float* __restrict__ Msk, float* __restrict__ OC)
{
  __shared__ float ks[NN*17];
  __shared__ float vs[NN*17];
  const int blk = blockIdx.x;
  const int qtr = blk & 3, h = (blk >> 2) & 7, b = blk >> 5;
  const int t = threadIdx.x;
  const float* kb = K_ + ((size_t)b*NN)*128 + h*16;
  const float* vb = V_ + ((size_t)b*NN)*128 + h*16;
  for (int i = t; i < NN*4; i += 256) {
    int n = i >> 2, d4 = (i & 3) << 2;
    f4 kv = *(const f4*)(kb + (size_t)n*128 + d4);
    f4 vv = *(const f4*)(vb + (size_t)n*128 + d4);
    #pragma unroll
    for (int j = 0; j < 4; j++) { ks[n*17 + d4 + j] = kv[j]; vs[n*17 + d4 + j] = vv[j]; }
  }
  __syncthreads();
  const int wv = t >> 6, ln = t & 63;
  const int p0 = qtr * 125;
  for (int p = p0 + wv; p < p0 + 125; p += 4) {
    const float* qr = Q + ((size_t)(b*PP + p))*128 + h*16;
    f4 q[4];
    #pragma unroll
    for (int j = 0; j < 4; j++) q[j] = *(const f4*)(qr + j*4);
    const float* mr = Msk + ((size_t)(b*PP + p))*NN;
    float s[8];
    #pragma unroll
    for (int j = 0; j < 8; j++) {
      int n = j*64 + ln;
      float a = -INFINITY;
      if (n < NN) {
        const float* kr = ks + n*17;
        float acc = 0.f;
        #pragma unroll
        for (int jj = 0; jj < 4; jj++)
          #pragma unroll
          for (int d = 0; d < 4; d++)
            acc += q[jj][d] * kr[jj*4 + d];
        a = acc*0.25f + mr[n];
      }
      s[j] = a;
    }
    float m = s[0];
    #pragma unroll
    for (int j = 1; j < 8; j++) m = fmaxf(m, s[j]);
    #pragma unroll
    for (int o = 32; o > 0; o >>= 1) m = fmaxf(m, __shfl_xor(m, o));
    float e[8]; float l = 0.f;
    #pragma unroll
    for (int j = 0; j < 8; j++) { e[j] = __expf(s[j] - m); l += e[j]; }
    #pragma unroll
    for (int o = 32; o > 0; o >>= 1) l += __shfl_xor(l, o);
    float out[16];
    #pragma unroll
    for (int d = 0; d < 16; d++) out[d] = 0.f;
    #pragma unroll
    for (int j = 0; j < 8; j++) {
      int n = j*64 + ln;
      if (n < NN) {
        const float* vr = vs + n*17;
        #pragma unroll
        for (int d = 0; d < 16; d++) out[d] += e[j] * vr[d];
      }
    }
    #pragma unroll
    for (int d = 0; d < 16; d++)
      #pragma unroll
      for (int o = 32; o > 0; o >>= 1) out[d] += __shfl_xor(out[d], o);
    if (ln == 0) {
      float inv = 1.f / l;
      float* orow = OC + ((size_t)(b*PP + p))*128 + h*16;
      #pragma unroll
      for (int d4 = 0; d4 < 16; d4 += 4) {
        f4 o;
        #pragma unroll
        for (int c = 0; c < 4; c++) o[c] = out[d4+c]*inv;
        *(f4*)(orow + d4) = o;
      }
    }
  }
}

// ---------------- fused per-batch FFN chain ----------------
__global__ __launch_bounds__(256) void k_ffn(
    const float* __restrict__ OC, const float* __restrict__ Wn, const float* __restrict__ Bn,
    const float* __restrict__ Wn2, const float* __restrict__ Bn2,
    const float* __restrict__ Wm, const float* __restrict__ Bm,
    float* __restrict__ MH)
{
  __shared__ float xs[64*132];
  __shared__ float hs[64*132];
  const int blk = blockIdx.x; const int b = blk >> 3, rb = blk & 7;
  const int r0 = rb*64;
  const int nv = min(64, PP - r0);
  const int t = threadIdx.x;
  const int tr = t >> 5, tc = t & 31;
  const float* ocb = OC + (size_t)b*PP*128;
  for (int i = t; i < 64*32; i += 256) {
    int r = i >> 5, k4 = (i & 31) << 2;
    f4 v = {0.f,0.f,0.f,0.f};
    if (r < nv) v = *(const f4*)(ocb + (size_t)(r0+r)*128 + k4);
    *(f4*)(xs + r*132 + k4) = v;
  }
  __syncthreads();
  // GEMM1: relu(xs @ new[b] + bias)
  {
    const float* W1 = Wn + (size_t)b*16384;
    float acc[8][4];
    #pragma unroll
    for (int i = 0; i < 8; i++)
      #pragma unroll
      for (int c = 0; c < 4; c++) acc[i][c] = 0.f;
    for (int k4 = 0; k4 < 128; k4 += 4) {
      f4 x[8], w[4];
      #pragma unroll
      for (int j = 0; j < 4; j++) w[j] = *(const f4*)(W1 + (size_t)(k4+j)*128 + tc*4);
      #pragma unroll
      for (int i = 0; i < 8; i++) x[i] = *(const f4*)(xs + (tr*8+i)*132 + k4);
      #pragma unroll
      for (int i = 0; i < 8; i++)
        #pragma unroll
        for (int j = 0; j < 4; j++)
          #pragma unroll
          for (int c = 0; c < 4; c++)
            acc[i][c] += x[i][j] * w[j][c];
    }
    f4 b1 = *(const f4*)(Bn + b*128 + tc*4);
    #pragma unroll
    for (int i = 0; i < 8; i++) {
      f4 o;
      #pragma unroll
      for (int c = 0; c < 4; c++) o[c] = fmaxf(acc[i][c] + b1[c], 0.f);
      *(f4*)(hs + (tr*8+i)*132 + tc*4) = o;
    }
  }
  __syncthreads();
  // GEMM2: hs @ new_2[b] + bias2 + residual(xs)
  float h2[8][4];
  {
    const float* W2 = Wn2 + (size_t)b*16384;
    float acc[8][4];
    #pragma unroll
    for (int i = 0; i < 8; i++)
      #pragma unroll
      for (int c = 0; c < 4; c++) acc[i][c] = 0.f;
    for (int k4 = 0; k4 < 128; k4 += 4) {
      f4 x[8], w[4];
      #pragma unroll
      for (int j = 0; j < 4; j++) w[j] = *(const f4*)(W2 + (size_t)(k4+j)*128 + tc*4);
      #pragma unroll
      for (int i = 0; i < 8; i++) x[i] = *(const f4*)(hs + (tr*8+i)*132 + k4);
      #pragma unroll
      for (int i = 0; i < 8; i++)
        #pragma unroll
        for (int j = 0; j < 4; j++)
          #pragma unroll
          for (int c = 0; c < 4; c++)
            acc[i][c] += x[i][j] * w[j][c];
    }
    f4 b2 = *(const f4*)(Bn2 + b*128 + tc*4);
    #pragma unroll
    for (int i = 0; i < 8; i++)
      #pragma unroll
      for (int c = 0; c < 4; c++)
        h2[i][c] = acc[i][c] + b2[c] + xs[(tr*8+i)*132 + tc*4 + c];
  }
  __syncthreads();
  #pragma unroll
  for (int i = 0; i < 8; i++) {
    f4 o;
    #pragma unroll
    for (int c = 0; c < 4; c++) o[c] = h2[i][c];
    *(f4*)(hs + (tr*8+i)*132 + tc*4) = o;
  }
  __syncthreads();
  // GEMM3: hs @ mhc_W + mhc_b -> MH
  {
    float acc[8][4];
    #pragma unroll
    for (int i = 0; i < 8; i++)
      #pragma unroll
      for (int c = 0; c < 4; c++) acc[i][c] = 0.f;
    for (int k4 = 0; k4 < 128; k4 += 4) {
      f4 x[8], w[4];
      #pragma unroll
      for (int j = 0; j < 4; j++) w[j] = *(const f4*)(Wm + (size_t)(k4+j)*128 + tc*4);
      #pragma unroll
      for (int i = 0; i < 8; i++) x[i] = *(const f4*)(hs + (tr*8+i)*132 + k4);
      #pragma unroll
      for (int i = 0; i < 8; i++)
        #pragma unroll
        for (int j = 0; j < 4; j++)
          #pragma unroll
          for (int c = 0; c < 4; c++)
            acc[i][c] += x[i][j] * w[j][c];
    }
    f4 b3 = *(const f4*)(Bm + tc*4);
    #pragma unroll
    for (int i = 0; i < 8; i++) {
      if (tr*8 + i < nv) {
        f4 o;
        #pragma unroll
        for (int c = 0; c < 4; c++) o[c] = acc[i][c] + b3[c];
        *(f4*)(MH + ((size_t)b*PP + r0 + tr*8 + i)*128 + tc*4) = o;
      }
    }
  }
}

// ---------------- final: score2 GEMM + tanh clip + mask + softmax ----------------
// Scores held entirely in registers: s[8 tiles][4 rows][2 cols] = 64 VGPR.
// Row softmax via width-32 shfl reductions (cols live across the 32 tc lanes).
__global__ __launch_bounds__(256, 3) void k_final(
    const float* __restrict__ MH, const float* __restrict__ EN,
    const float* __restrict__ Msk, float* __restrict__ OUT)
{
  __shared__ float ms[32*132];   // 16.9 KB
  __shared__ float es[64*132];   // 33.8 KB
  const int blk = blockIdx.x; const int b = blk >> 4, rb = blk & 15;
  const int r0 = rb*32; const int nv = min(32, PP - r0);
  const int t = threadIdx.x;
  const int tr = t >> 5, tc = t & 31;
  const float* mhb = MH + (size_t)(b*PP + r0)*128;
  for (int i = t; i < 32*32; i += 256) {
    int r = i >> 5, k4 = (i & 31) << 2;
    f4 v = {0.f,0.f,0.f,0.f};
    if (r < nv) v = *(const f4*)(mhb + (size_t)r*128 + k4);
    *(f4*)(ms + r*132 + k4) = v;
  }
  const float* enb = EN + (size_t)b*NN*128;
  float s[8][4][2];
  #pragma unroll
  for (int nt = 0; nt < 8; nt++) {
    const int n0 = nt*64;
    __syncthreads();
    for (int i = t; i < 64*32; i += 256) {
      int n = i >> 5, k4 = (i & 31) << 2;
      f4 v = {0.f,0.f,0.f,0.f};
      if (n0 + n < NN) v = *(const f4*)(enb + (size_t)(n0+n)*128 + k4);
      *(f4*)(es + n*132 + k4) = v;
    }
    __syncthreads();
    float acc[4][2];
    #pragma unroll
    for (int i = 0; i < 4; i++) { acc[i][0] = 0.f; acc[i][1] = 0.f; }
    #pragma unroll 8
    for (int k4 = 0; k4 < 128; k4 += 4) {
      f4 x[4];
      #pragma unroll
      for (int i = 0; i < 4; i++) x[i] = *(const f4*)(ms + (tr*4+i)*132 + k4);
      f4 e0 = *(const f4*)(es + tc*132 + k4);
      f4 e1 = *(const f4*)(es + (tc+32)*132 + k4);
      #pragma unroll
      for (int i = 0; i < 4; i++)
        #pragma unroll
        for (int j = 0; j < 4; j++) {
          acc[i][0] += x[i][j]*e0[j];
          acc[i][1] += x[i][j]*e1[j];
        }
    }
    #pragma unroll
    for (int i = 0; i < 4; i++) {
      s[nt][i][0] = acc[i][0];
      s[nt][i][1] = acc[i][1];
    }
  }
  // clip + mask, in registers
  const float* mkb = Msk + (size_t)(b*PP + r0)*NN;
  #pragma unroll
  for (int nt = 0; nt < 8; nt++)
    #pragma unroll
    for (int i = 0; i < 4; i++)
      #pragma unroll
      for (int c = 0; c < 2; c++) {
        int r = tr*4 + i, n = nt*64 + tc + c*32;
        float val = -INFINITY;
        if (r < nv && n < NN) {
          // 10*tanh(s/sqrt(128)) = 10 - 20/(exp(s*2/sqrt(128)) + 1)  (NaN-free)
          float E = __expf(s[nt][i][c] * 0.17677669529663687f);
          val = 10.f - 20.f/(E + 1.f) + mkb[(size_t)r*NN + n];
        }
        s[nt][i][c] = val;
      }
  // per-row softmax: reduce across the 32 tc lanes (width 32 keeps tr pairs separate)
  float* ob = OUT + (size_t)(b*PP + r0)*NN;
  #pragma unroll
  for (int i = 0; i < 4; i++) {
    float m = -INFINITY;
    #pragma unroll
    for (int nt = 0; nt < 8; nt++)
      #pragma unroll
      for (int c = 0; c < 2; c++) m = fmaxf(m, s[nt][i][c]);
    #pragma unroll
    for (int o = 16; o > 0; o >>= 1) m = fmaxf(m, __shfl_xor(m, o, 32));
    float l = 0.f;
    #pragma unroll
    for (int nt = 0; nt < 8; nt++)
      #pragma unroll
      for (int c = 0; c < 2; c++) {
        float e_ = __expf(s[nt][i][c] - m);
        s[nt][i][c] = e_;
        l += e_;
      }
    #pragma unroll
    for (int o = 16; o > 0; o >>= 1) l += __shfl_xor(l, o, 32);
    const int r = tr*4 + i;
    if (r < nv) {
      float inv = 1.f / l;
      float* orow = ob + (size_t)r*NN;
      #pragma unroll
      for (int nt = 0; nt < 8; nt++)
        #pragma unroll
        for (int c = 0; c < 2; c++) {
          int n = nt*64 + tc + c*32;
          if (n < NN) orow[n] = s[nt][i][c] * inv;
        }
    }
  }
}

extern "C" void kernel_launch(void* const* d_in, const int* in_sizes, int n_in,
                              void* d_out, int out_size, void* d_ws, size_t ws_size,
                              hipStream_t stream) {
  const float* eln  = (const float*)d_in[0];
  const float* load = (const float*)d_in[1];
  const float* mask = (const float*)d_in[2];
  const float* en   = (const float*)d_in[3];
  const float* Wq   = (const float*)d_in[4];
  const float* Wk   = (const float*)d_in[5];
  const float* Wv   = (const float*)d_in[6];
  const float* Wm   = (const float*)d_in[7];
  const float* Bm   = (const float*)d_in[8];
  const float* Wn   = (const float*)d_in[9];
  const float* Bn   = (const float*)d_in[10];
  const float* Wn2  = (const float*)d_in[11];
  const float* Bn2  = (const float*)d_in[12];
  float* out = (float*)d_out;
  float* ws  = (float*)d_ws;
  float* Q   = ws;
  float* K_  = ws + 4096000;     // 64*500*128
  float* V_  = ws + 8200192;     // + 64*501*128
  float* OC  = ws + 12304384;    // + 64*501*128
  float* MH  = ws + 16400384;    // + 64*500*128
  hipLaunchKernelGGL(k_proj_q,  dim3(500),  dim3(256), 0, stream, eln, load, Wq, Q);
  hipLaunchKernelGGL(k_proj_kv, dim3(501),  dim3(256), 0, stream, en, Wk, Wv, K_, V_);
  hipLaunchKernelGGL(k_attn,    dim3(2048), dim3(256), 0, stream, Q, K_, V_, mask, OC);
  hipLaunchKernelGGL(k_ffn,     dim3(512),  dim3(256), 0, stream, OC, Wn, Bn, Wn2, Bn2, Wm, Bm, MH);
  hipLaunchKernelGGL(k_final,   dim3(1024), dim3(256), 0, stream, MH, en, mask, out);
}